// Round 8
// baseline (16.053 us; speedup 1.0000x reference)
//
#include <hip/hip_runtime.h>
#include <hip/hip_bf16.h>

#define SPIN_LEN 365
#define TRAIN_LEN 40000
#define ML 2.9086f
#define SL 1.898f
#define L2E 1.4426950408889634f
#define LN2 0.6931471805599453f

#define WARM 64
#define BLK 256
#define NENT (BLK + WARM)                 /* 320 LDS entries */

#define STD_N     (TRAIN_LEN - SPIN_LEN)  /* 39635 */
#define STD_BODY4 ((TRAIN_LEN - 368) >> 2)/* 9908 float4s from y+368 */
#define STD_FULL  38                      /* 38*256 = 9728 */
#define STD_TAIL  (STD_BODY4 - STD_FULL * BLK) /* 180 */

#define EXP2F(v) __builtin_amdgcn_exp2f(v)
#define RCPF(v)  __builtin_amdgcn_rcpf(v)

// One launch, 197 blocks:
//  - block NB (last): dedicated std block — reads y ONCE (158KB), 4-acc
//    reduction, writes the two std-dependent streams (obs_std, h_nout col1).
//  - blocks 0..NB-1: scan blocks — no y work at all; barrier covers only the
//    2.5KB x-load + ent[] fill. 64-step warm-up of the contraction
//    (|dc'/dc| <= 0.845, err <= 8*0.845^64 ~ 1.7e-4 << bf16 floor).
//    Interior blocks take a peeled fast path: c=0 only at step 0 (c1=u1>0),
//    so cpos/gate selects vanish from the carry chain.
__global__ __launch_bounds__(BLK) void fused_kernel(
        const float* __restrict__ x, const float* __restrict__ y,
        const float* __restrict__ wom, const float* __restrict__ wlm,
        const float* __restrict__ wfm, const float* __restrict__ b0,
        const float* __restrict__ b2, const int* __restrict__ tlp,
        float* __restrict__ out, int T) {
    const int tid = threadIdx.x;
    const int b   = blockIdx.x;
    const int NB  = (int)gridDim.x - 1;
    int tl = tlp[0]; if (tl < 0) tl = 0;
    size_t Ts = (size_t)T;

    if (b == NB) {
        // ---------------- std block ----------------
        const float4* y4 = (const float4*)(y + 368);
        float s1a = 0.f, s1b = 0.f, s2a = 0.f, s2b = 0.f, s2c = 0.f, s2d = 0.f;
        #pragma unroll
        for (int k = 0; k < STD_FULL; ++k) {
            float4 v = y4[tid + (k << 8)];
            float a0 = v.x - 0.5f, a1 = v.y - 0.5f, a2 = v.z - 0.5f, a3 = v.w - 0.5f;
            s1a += a0 + a1; s1b += a2 + a3;
            s2a = fmaf(a0, a0, s2a); s2b = fmaf(a1, a1, s2b);
            s2c = fmaf(a2, a2, s2c); s2d = fmaf(a3, a3, s2d);
        }
        if (tid < STD_TAIL) {
            float4 v = y4[tid + STD_FULL * BLK];
            float a0 = v.x - 0.5f, a1 = v.y - 0.5f, a2 = v.z - 0.5f, a3 = v.w - 0.5f;
            s1a += a0 + a1; s1b += a2 + a3;
            s2a = fmaf(a0, a0, s2a); s2b = fmaf(a1, a1, s2b);
            s2c = fmaf(a2, a2, s2c); s2d = fmaf(a3, a3, s2d);
        }
        if (tid < 3) {                     // head elems y[365..367]
            float v = y[SPIN_LEN + tid] - 0.5f;
            s1a += v; s2a = fmaf(v, v, s2a);
        }
        float s1 = s1a + s1b;
        float s2 = (s2a + s2b) + (s2c + s2d);
        for (int o = 32; o > 0; o >>= 1) {
            s1 += __shfl_down(s1, o, 64);
            s2 += __shfl_down(s2, o, 64);
        }
        __shared__ float sh1[BLK / 64], sh2[BLK / 64];
        int wave = tid >> 6;
        if ((tid & 63) == 0) { sh1[wave] = s1; sh2[wave] = s2; }
        __syncthreads();
        float S1 = (sh1[0] + sh1[1]) + (sh1[2] + sh1[3]);
        float S2 = (sh2[0] + sh2[1]) + (sh2[2] + sh2[3]);
        float nf = (float)STD_N;
        float sv = sqrtf(fmaxf((S2 - S1 * S1 / nf) / (nf - 1.0f), 0.0f));
        for (int i = tid; i < T; i += BLK) {
            float svi = (i >= tl) ? sv : 0.0f;
            out[12 * Ts + i] = svi;                       // obs_std stream
            out[10 * Ts + 2 * (size_t)i + 1] = svi;       // h_nout col 1
        }
        return;
    }

    // ---------------- scan blocks ----------------
    const int t0 = b * BLK;
    const int t  = t0 + tid;

    float eo = __expf(wom[0]);
    float el = __expf(wlm[0]);
    float ef = __expf(wfm[0]);
    float iden = RCPF(eo + el + ef);
    float oo   = eo * iden;
    float ol1  = el * iden;
    float koo  = 1.0f - oo;
    float sb2  = b2[0] * (1.0f / SL);
    float base = fmaf(-ML, sb2, b0[0]);

    __shared__ float4 ent[NENT];
    const float2* xp = (const float2*)x;
    const bool fast = (t0 - WARM >= tl) && (t0 + BLK + WARM <= T);

    int ia = t0 - WARM + tid;
    int ib = ia + BLK;
    if (!fast) {
        ia = ia < 0 ? 0 : (ia > T - 1 ? T - 1 : ia);
        ib = ib > T - 1 ? T - 1 : ib;
    }
    float2 ua = xp[ia];
    float2 ub = make_float2(0.f, 0.f);
    if (tid < WARM) ub = xp[ib];

    {   // ent[i] = (u1, u2, ol*L2E, koo-ol-1)
        float ol3 = fmaf(ua.y, sb2, base);
        float sig = RCPF(1.0f + EXP2F(-ol3 * L2E));
        float ol  = ol1 * sig;
        ent[tid] = make_float4(ua.x, ua.y, ol * L2E, koo - ol - 1.0f);
        if (tid < WARM) {
            float ol3b = fmaf(ub.y, sb2, base);
            float sigb = RCPF(1.0f + EXP2F(-ol3b * L2E));
            float olb  = ol1 * sigb;
            ent[BLK + tid] = make_float4(ub.x, ub.y, olb * L2E, koo - olb - 1.0f);
        }
    }
    __syncthreads();

    float c;
    float4 e;
    if (fast) {
        c = ent[tid].x;                    // peeled step 0: c=0 -> c1 = u1
        e = ent[tid + 1];
        #pragma unroll 7
        for (int k = 1; k < WARM; ++k) {
            float4 en = ent[tid + k + 1];  // k=63 fetches the epilogue entry
            float u1 = e.x, u2 = e.y, olL = e.z, qq = e.w;
            float rc  = RCPF(c);
            float u2L = u2 * L2E;
            float E   = EXP2F(fmaf(-u2L, rc, olL));          // exp(ol - u2/c)
            float c1B = fmaf(fmaxf(qq + E, 0.0f), c, u1);    // elu branch
            float c1A = fmaxf(fmaf(koo, c, -u2), 0.0f) + u1; // r branch
            c = (olL * c > u2L) ? c1A : c1B;
            e = en;
        }
    } else {
        c = 0.0f;
        e = ent[tid];
        #pragma unroll 4
        for (int k = 0; k < WARM; ++k) {
            float4 en = ent[tid + k + 1];
            float u1 = e.x, u2 = e.y, olL = e.z, qq = e.w;
            bool  cpos = c > 0.0f;
            float rc  = RCPF(cpos ? c : 1.0f);
            float u2L = u2 * L2E;
            float E   = EXP2F(fmaf(-u2L, rc, olL));
            float c1B = fmaf(fmaxf(qq + E, 0.0f), c, u1);
            float c1A = fmaxf(fmaf(koo, c, -u2), 0.0f) + u1;
            float c1  = cpos ? ((olL * c > u2L) ? c1A : c1B) : u1;
            int i = t - WARM + k;
            c = (i >= tl) ? c1 : c;        // time_lag gate (also kills i<0)
            e = en;
        }
    }

    if (t >= T) return;

    // epilogue: outputs at t from carry c and entry e == ent[tid+WARM]
    float u2 = e.y, olL = e.z;
    float ol = olL * LN2;
    bool  cpos = c > 0.0f;
    float rc   = RCPF(cpos ? c : 1.0f);
    float E    = EXP2F(fmaf(-u2 * L2E, rc, olL));
    float olc_pre = cpos ? ((olL * c > u2 * L2E) ? u2 * rc : (ol + 1.0f - E)) : ol;
    float f   = fmaxf(koo - olc_pre, 0.0f);
    float olc = fmaxf(olc_pre, 0.0f);

    bool mask = t >= tl;
    float h = mask ? oo * c : 0.0f;

    out[t]            = h;
    out[Ts + t]       = mask ? c : 0.0f;
    out[2 * Ts + t]   = mask ? ol * c : 0.0f;
    out[3 * Ts + t]   = mask ? olc * c : 0.0f;
    out[4 * Ts + t]   = 0.0f;
    out[5 * Ts + t]   = 0.0f;
    out[6 * Ts + t]   = mask ? oo : 0.0f;
    out[7 * Ts + t]   = mask ? ol : 0.0f;
    out[8 * Ts + t]   = mask ? olc : 0.0f;
    out[9 * Ts + t]   = mask ? f : 0.0f;
    out[10 * Ts + 2 * (size_t)t] = h;      // h_nout col 0 (col 1: std block)
}

extern "C" void kernel_launch(void* const* d_in, const int* in_sizes, int n_in,
                              void* d_out, int out_size, void* d_ws, size_t ws_size,
                              hipStream_t stream) {
    const float* x   = (const float*)d_in[0];
    const float* y   = (const float*)d_in[1];
    const float* wom = (const float*)d_in[2];
    const float* wlm = (const float*)d_in[3];
    const float* wfm = (const float*)d_in[4];
    const float* b0  = (const float*)d_in[5];
    const float* b2  = (const float*)d_in[6];
    // d_in[7] = theltaC (unused), d_in[8] = epoch (unused)
    const int* tl = (const int*)d_in[9];
    float* out = (float*)d_out;
    int T = in_sizes[1];

    int nb = (T + BLK - 1) / BLK;          // scan blocks
    fused_kernel<<<nb + 1, BLK, 0, stream>>>(
        x, y, wom, wlm, wfm, b0, b2, tl, out, T);
}

// Round 9
// 12.812 us; speedup vs baseline: 1.2530x; 1.2530x over previous
//
#include <hip/hip_runtime.h>
#include <hip/hip_bf16.h>

#define SPIN_LEN 365
#define TRAIN_LEN 40000
#define ML 2.9086f
#define SL 1.898f
#define L2E 1.4426950408889634f
#define LN2 0.6931471805599453f

#define WARM 64
#define BLK 256
#define NENT (BLK + WARM)                 /* 320 LDS entries */

#define STD_N     (TRAIN_LEN - SPIN_LEN)  /* 39635 */
#define STD_BODY4 ((TRAIN_LEN - 368) >> 2)/* 9908 float4s from y+368 */
#define STD_FULL  38                      /* 38*256 = 9728 */
#define STD_TAIL  (STD_BODY4 - STD_FULL * BLK) /* 180 */

#define EXP2F(v) __builtin_amdgcn_exp2f(v)
#define RCPF(v)  __builtin_amdgcn_rcpf(v)

// Single kernel, 196 blocks (<=1 block/CU -> VGPR pressure is free).
// Structure: [x load -> ent fill] barrier1 [y loads + std accum (branchless,
// clamped+masked) FUSED in one basic block with the 64-step scan -> scheduler
// hides y latency in the scan chain's idle issue slots -> wave partials]
// barrier2 [combine sv, 13 coalesced stream writes].
// Scan: 64-step warm-up of the contraction (|dc'/dc| <= 0.845, err <=
// 8*0.845^64 ~ 1.7e-4 << bf16 floor). Block-redundant std: identical order
// in every block => deterministic.
__global__ __launch_bounds__(BLK, 1) void fused_kernel(
        const float* __restrict__ x, const float* __restrict__ y,
        const float* __restrict__ wom, const float* __restrict__ wlm,
        const float* __restrict__ wfm, const float* __restrict__ b0,
        const float* __restrict__ b2, const int* __restrict__ tlp,
        float* __restrict__ out, int T) {
    const int tid = threadIdx.x;
    const int t0  = blockIdx.x * BLK;
    const int t   = t0 + tid;
    int tl = tlp[0]; if (tl < 0) tl = 0;

    // block-uniform scalars (uniform addresses -> s_loads)
    float eo = __expf(wom[0]);
    float el = __expf(wlm[0]);
    float ef = __expf(wfm[0]);
    float iden = RCPF(eo + el + ef);
    float oo   = eo * iden;
    float ol1  = el * iden;
    float koo  = 1.0f - oo;
    float sb2  = b2[0] * (1.0f / SL);
    float base = fmaf(-ML, sb2, b0[0]);

    __shared__ float4 ent[NENT];
    __shared__ float sh1[BLK / 64], sh2[BLK / 64];

    // ---- x loads + ent fill (the only thing barrier1 must cover) ----
    const float2* xp = (const float2*)x;
    int ia = t0 - WARM + tid;
    ia = ia < 0 ? 0 : (ia > T - 1 ? T - 1 : ia);
    float2 ua = xp[ia];
    int ib = t0 - WARM + BLK + tid;
    ib = ib > T - 1 ? T - 1 : ib;
    float2 ub = xp[ib];                    // only lanes <WARM store it

    {   // ent[i] = (u1, u2, ol*L2E, koo-ol-1)
        float ol3 = fmaf(ua.y, sb2, base);
        float sig = RCPF(1.0f + EXP2F(-ol3 * L2E));
        float ol  = ol1 * sig;
        ent[tid] = make_float4(ua.x, ua.y, ol * L2E, koo - ol - 1.0f);
        if (tid < WARM) {
            float ol3b = fmaf(ub.y, sb2, base);
            float sigb = RCPF(1.0f + EXP2F(-ol3b * L2E));
            float olb  = ol1 * sigb;
            ent[BLK + tid] = make_float4(ub.x, ub.y, olb * L2E, koo - olb - 1.0f);
        }
    }
    __syncthreads();                       // barrier1: drains only x loads

    // ======== single branchless region: y-std work + scan chain ========
    const float4* y4 = (const float4*)(y + 368);
    float s1a = 0.f, s1b = 0.f, s2a = 0.f, s2b = 0.f;
    #pragma unroll
    for (int k = 0; k < STD_FULL; ++k) {
        float4 v = y4[tid + (k << 8)];     // unconditional, in-bounds
        float a0 = v.x - 0.5f, a1 = v.y - 0.5f, a2 = v.z - 0.5f, a3 = v.w - 0.5f;
        s1a += a0 + a1; s1b += a2 + a3;
        s2a = fmaf(a0, a0, fmaf(a1, a1, s2a));
        s2b = fmaf(a2, a2, fmaf(a3, a3, s2b));
    }
    {   // tail: clamped address, masked contribution (branch-free)
        int q = tid < STD_TAIL ? tid + STD_FULL * BLK : STD_FULL * BLK;
        float m = tid < STD_TAIL ? 1.0f : 0.0f;
        float4 v = y4[q];
        float a0 = (v.x - 0.5f) * m, a1 = (v.y - 0.5f) * m;
        float a2 = (v.z - 0.5f) * m, a3 = (v.w - 0.5f) * m;
        s1a += a0 + a1; s1b += a2 + a3;
        s2a = fmaf(a0, a0, fmaf(a1, a1, s2a));
        s2b = fmaf(a2, a2, fmaf(a3, a3, s2b));
    }
    {   // head elems y[365..367]: masked
        float m = tid < 3 ? 1.0f : 0.0f;
        float v = (y[SPIN_LEN + (tid < 3 ? tid : 0)] - 0.5f) * m;
        s1a += v; s2a = fmaf(v, v, s2a);
    }

    // 64-step warm-up scan (independent of y work -> scheduler interleaves)
    float c = 0.0f;
    float4 e = ent[tid];
    #pragma unroll
    for (int k = 0; k < WARM; ++k) {
        float4 en = ent[tid + k + 1];      // k=63 fetches the epilogue entry
        float u1 = e.x, u2 = e.y, olL = e.z, qq = e.w;
        bool  cpos = c > 0.0f;
        float rc  = RCPF(cpos ? c : 1.0f);
        float u2L = u2 * L2E;
        float E   = EXP2F(fmaf(-u2L, rc, olL));          // exp(ol - u2/c)
        float c1B = fmaf(fmaxf(qq + E, 0.0f), c, u1);    // elu branch
        float c1A = fmaxf(fmaf(koo, c, -u2), 0.0f) + u1; // r branch
        float c1  = cpos ? ((olL * c > u2L) ? c1A : c1B) : u1;
        c = ((t - WARM + k) >= tl) ? c1 : c;             // gate (kills i<tl)
        e = en;
    }

    // wave-level std partials
    float s1 = s1a + s1b, s2 = s2a + s2b;
    for (int o = 32; o > 0; o >>= 1) {
        s1 += __shfl_down(s1, o, 64);
        s2 += __shfl_down(s2, o, 64);
    }
    int wave = tid >> 6;
    if ((tid & 63) == 0) { sh1[wave] = s1; sh2[wave] = s2; }
    __syncthreads();                       // barrier2

    // every thread combines the 4 wave partials (deterministic)
    float S1 = (sh1[0] + sh1[1]) + (sh1[2] + sh1[3]);
    float S2 = (sh2[0] + sh2[1]) + (sh2[2] + sh2[3]);
    float nf = (float)STD_N;
    float obsstd = sqrtf(fmaxf((S2 - S1 * S1 / nf) / (nf - 1.0f), 0.0f));

    if (t >= T) return;

    // ---- epilogue: outputs at t from carry c and entry e == ent[tid+WARM] ----
    float u2 = e.y, olL = e.z;
    float ol = olL * LN2;
    bool  cpos = c > 0.0f;
    float rc   = RCPF(cpos ? c : 1.0f);
    float E    = EXP2F(fmaf(-u2 * L2E, rc, olL));
    float olc_pre = cpos ? ((olL * c > u2 * L2E) ? u2 * rc : (ol + 1.0f - E)) : ol;
    float f   = fmaxf(koo - olc_pre, 0.0f);
    float olc = fmaxf(olc_pre, 0.0f);

    bool mask = t >= tl;
    float h  = mask ? oo * c : 0.0f;
    float sv = mask ? obsstd : 0.0f;

    size_t Ts = (size_t)T;
    out[t]            = h;
    out[Ts + t]       = mask ? c : 0.0f;
    out[2 * Ts + t]   = mask ? ol * c : 0.0f;
    out[3 * Ts + t]   = mask ? olc * c : 0.0f;
    out[4 * Ts + t]   = 0.0f;
    out[5 * Ts + t]   = 0.0f;
    out[6 * Ts + t]   = mask ? oo : 0.0f;
    out[7 * Ts + t]   = mask ? ol : 0.0f;
    out[8 * Ts + t]   = mask ? olc : 0.0f;
    out[9 * Ts + t]   = mask ? f : 0.0f;
    ((float2*)(out + 10 * Ts))[t] = make_float2(h, sv);   // h_nout (T,2)
    out[12 * Ts + t]  = sv;
}

extern "C" void kernel_launch(void* const* d_in, const int* in_sizes, int n_in,
                              void* d_out, int out_size, void* d_ws, size_t ws_size,
                              hipStream_t stream) {
    const float* x   = (const float*)d_in[0];
    const float* y   = (const float*)d_in[1];
    const float* wom = (const float*)d_in[2];
    const float* wlm = (const float*)d_in[3];
    const float* wfm = (const float*)d_in[4];
    const float* b0  = (const float*)d_in[5];
    const float* b2  = (const float*)d_in[6];
    // d_in[7] = theltaC (unused), d_in[8] = epoch (unused)
    const int* tl = (const int*)d_in[9];
    float* out = (float*)d_out;
    int T = in_sizes[1];

    fused_kernel<<<(T + BLK - 1) / BLK, BLK, 0, stream>>>(
        x, y, wom, wlm, wfm, b0, b2, tl, out, T);
}